// Round 1
// baseline (2473.548 us; speedup 1.0000x reference)
//
#include <hip/hip_runtime.h>
#include <math.h>

#define NG   2000
#define EG_  128000
#define NE_  130000      // EG_ + NG (edges incl. self-loops)
#define NEP  130048      // padded
#define T1_  7

// ---------------------------------------------------------------------------
// helpers
// ---------------------------------------------------------------------------
__device__ __forceinline__ void edge_sd(int g, int e, const int* __restrict__ eg,
                                        const int* __restrict__ ed, int& s, int& d) {
  if (e >= EG_) { s = e - EG_; d = s; return; }
  const int* b = (g == 0) ? eg : (ed + (size_t)(g - 1) * 2 * EG_);
  s = b[e]; d = b[EG_ + e];
}

__device__ __forceinline__ float blk_red256(float v) {
  __shared__ float red[256];
  int tid = threadIdx.x;
  red[tid] = v; __syncthreads();
  for (int s = 128; s > 0; s >>= 1) { if (tid < s) red[tid] += red[tid + s]; __syncthreads(); }
  float r = red[0]; __syncthreads();
  return r;
}

__device__ __forceinline__ float sigm(float x) { return 1.f / (1.f + expf(-x)); }

// ---------------------------------------------------------------------------
// CSR build (8 graphs: g=0 gene, g=1..7 drug t=g-1)
// ---------------------------------------------------------------------------
__global__ __launch_bounds__(256) void csr_count_k(const int* __restrict__ eg,
                                                   const int* __restrict__ ed,
                                                   int* __restrict__ cnt) {
  int e = blockIdx.x * 256 + threadIdx.x;
  int g = blockIdx.y;
  if (e >= NE_) return;
  int s, d; edge_sd(g, e, eg, ed, s, d);
  atomicAdd(&cnt[g * 2048 + d], 1);
}

__global__ __launch_bounds__(256) void csr_scan_k(const int* __restrict__ cnt,
                                                  int* __restrict__ rp) {
  int g = blockIdx.x, tid = threadIdx.x;
  const int* c = cnt + g * 2048;
  int* r = rp + g * 2048;
  int loc[8]; int s = 0;
  int base = tid * 8;
#pragma unroll
  for (int i = 0; i < 8; ++i) { loc[i] = s; int idx = base + i; s += (idx < NG) ? c[idx] : 0; }
  __shared__ int ps[256];
  ps[tid] = s; __syncthreads();
  for (int st = 1; st < 256; st <<= 1) {
    int v = (tid >= st) ? ps[tid - st] : 0; __syncthreads();
    ps[tid] += v; __syncthreads();
  }
  int excl = ps[tid] - s;
#pragma unroll
  for (int i = 0; i < 8; ++i) { int idx = base + i; if (idx < NG) r[idx] = excl + loc[i]; }
  if (tid == 255) r[NG] = ps[255];
}

__global__ __launch_bounds__(256) void csr_fill_k(const int* __restrict__ eg,
                                                  const int* __restrict__ ed,
                                                  const int* __restrict__ rp,
                                                  int* __restrict__ cur,
                                                  int* __restrict__ ce) {
  int e = blockIdx.x * 256 + threadIdx.x;
  int g = blockIdx.y;
  if (e >= NE_) return;
  int s, d; edge_sd(g, e, eg, ed, s, d);
  int pos = rp[g * 2048 + d] + atomicAdd(&cur[g * 2048 + d], 1);
  ce[(size_t)g * NEP + pos] = e;
}

// ---------------------------------------------------------------------------
// GCN degree / dinv
// ---------------------------------------------------------------------------
__global__ __launch_bounds__(256) void deg_k(const int* __restrict__ eg,
                                             const float* __restrict__ w,
                                             float* __restrict__ deg) {
  int e = blockIdx.x * 256 + threadIdx.x;
  if (e >= NE_) return;
  int d; float wv;
  if (e < EG_) { d = eg[EG_ + e]; wv = w[e]; } else { d = e - EG_; wv = 2.f; }
  atomicAdd(&deg[d], wv);
}

__global__ __launch_bounds__(256) void dinv_k(const float* __restrict__ deg,
                                              float* __restrict__ dinv) {
  int v = blockIdx.x * 256 + threadIdx.x;
  if (v >= NG) return;
  float dg = deg[v];
  dinv[v] = dg > 0.f ? 1.f / sqrtf(dg) : 0.f;
}

// ---------------------------------------------------------------------------
// Generic tiled fp32 GEMM.  C[M,N] = A[M,K] @ (BT ? W[N,K]^T : B[K,N])
// BM=128, BK=32, TM=8 fixed; 256 threads.
// SPLITK: grid.z = K-chunks, store transposed partials Ct[z][N][ldct].
// else : grid.z = batch, epilogue bias+act, row-major store.
// ---------------------------------------------------------------------------
template<int BN, int TN, bool BT, bool SPLITK>
__global__ __launch_bounds__(256) void gemm_k(
    const float* __restrict__ A, long sA,
    const float* __restrict__ Bm, long sB,
    const float* __restrict__ bias, int sBias,
    float* __restrict__ C, long sC,
    int M, int N, int K, int act, int KC, int ldct) {
  constexpr int BM = 128, BK = 32, TM = 8;
  __shared__ float As[BK][BM + 1];
  __shared__ float Bs[BK][BN + 1];
  int tid = threadIdx.x;
  int tc = tid & 15, tr = tid >> 4;
  int m0 = blockIdx.x * BM, n0 = blockIdx.y * BN;
  int z = blockIdx.z;
  const float* Ap; const float* Bp; const float* bp = nullptr;
  int kbeg, kend;
  if (SPLITK) { Ap = A; Bp = Bm; kbeg = z * KC; kend = min(K, kbeg + KC); }
  else {
    Ap = A + (long)z * sA; Bp = Bm + (long)z * sB;
    if (bias) bp = bias + (long)z * sBias;
    kbeg = 0; kend = K;
  }
  float acc[TM][TN] = {};
  for (int k0 = kbeg; k0 < kend; k0 += BK) {
    __syncthreads();
    for (int i = tid; i < BM * BK; i += 256) {
      int m = i >> 5, k = i & 31;
      int gm = m0 + m, gk = k0 + k;
      As[k][m] = (gm < M && gk < kend) ? Ap[(long)gm * K + gk] : 0.f;
    }
    if (BT) {
      for (int i = tid; i < BN * BK; i += 256) {
        int n = i >> 5, k = i & 31;
        int gn = n0 + n, gk = k0 + k;
        Bs[k][n] = (gn < N && gk < kend) ? Bp[(long)gn * K + gk] : 0.f;
      }
    } else {
      for (int i = tid; i < BK * BN; i += 256) {
        int k = i / BN, n = i % BN;
        int gk = k0 + k, gn = n0 + n;
        Bs[k][n] = (gk < kend && gn < N) ? Bp[(long)gk * N + gn] : 0.f;
      }
    }
    __syncthreads();
#pragma unroll
    for (int kk = 0; kk < BK; ++kk) {
      float a[TM], b[TN];
#pragma unroll
      for (int i = 0; i < TM; ++i) a[i] = As[kk][tr * TM + i];
#pragma unroll
      for (int j = 0; j < TN; ++j) b[j] = Bs[kk][tc * TN + j];
#pragma unroll
      for (int i = 0; i < TM; ++i)
#pragma unroll
        for (int j = 0; j < TN; ++j) acc[i][j] = fmaf(a[i], b[j], acc[i][j]);
    }
  }
  if (SPLITK) {
    float* Cz = C;
#pragma unroll
    for (int j = 0; j < TN; ++j) {
      int gc = n0 + tc * TN + j;
      if (gc >= N) continue;
#pragma unroll
      for (int i = 0; i < TM; ++i) {
        int gm = m0 + tr * TM + i;
        if (gm < M) Cz[((long)z * N + gc) * ldct + gm] = acc[i][j];
      }
    }
  } else {
    float* Cp = C + (long)z * sC;
#pragma unroll
    for (int i = 0; i < TM; ++i) {
      int gm = m0 + tr * TM + i;
      if (gm >= M) continue;
#pragma unroll
      for (int j = 0; j < TN; ++j) {
        int gc = n0 + tc * TN + j;
        if (gc >= N) continue;
        float v = acc[i][j] + (bp ? bp[gc] : 0.f);
        if (act == 1) v = fmaxf(v, 0.f);
        else if (act == 2) v = sigm(v);
        Cp[(long)gm * N + gc] = v;
      }
    }
  }
}

// ---------------------------------------------------------------------------
// GCN aggregation: out[v,c] = act(dinv[v] * sum_e w_e*dinv[src]*h[src,c] + b[c])
// ---------------------------------------------------------------------------
__global__ void gcn_agg_k(const int* __restrict__ rp, const int* __restrict__ ce,
                          const int* __restrict__ eg, const float* __restrict__ w,
                          const float* __restrict__ dinv, const float* __restrict__ h,
                          const float* __restrict__ bias, float* __restrict__ out,
                          int N, int act) {
  int v = blockIdx.x, c = threadIdx.x;
  if (c >= N) return;
  int beg = rp[v], end = rp[v + 1];
  float acc = 0.f;
  for (int i = beg; i < end; ++i) {
    int e = ce[i];
    int s; float wv;
    if (e < EG_) { s = eg[e]; wv = w[e]; } else { s = e - EG_; wv = 2.f; }
    acc += wv * dinv[s] * h[(long)s * N + c];
  }
  float r = dinv[v] * acc + bias[c];
  out[(long)v * N + c] = (act == 1) ? fmaxf(r, 0.f) : sigm(r);
}

// ---------------------------------------------------------------------------
// GAT attention pieces
// ---------------------------------------------------------------------------
template<int H>
__global__ void att_scores_k(const float* __restrict__ h, const float* __restrict__ a_s,
                             const float* __restrict__ a_d, float* __restrict__ os,
                             float* __restrict__ od) {
  int v = blockIdx.x, t = blockIdx.y, l = threadIdx.x;
  const float* hp = h + ((long)t * NG + v) * H;
  const float* asp = a_s + t * H;
  const float* adp = a_d + t * H;
  float vs = 0.f, vd = 0.f;
  for (int c = l; c < H; c += 64) { float hv = hp[c]; vs += hv * asp[c]; vd += hv * adp[c]; }
  for (int o = 32; o; o >>= 1) { vs += __shfl_down(vs, o); vd += __shfl_down(vd, o); }
  if (l == 0) { os[t * 2048 + v] = vs; od[t * 2048 + v] = vd; }
}

__global__ __launch_bounds__(256) void edge_p_k(const int* __restrict__ ed,
                                                const float* __restrict__ os,
                                                const float* __restrict__ od,
                                                float* __restrict__ p,
                                                float* __restrict__ den) {
  int e = blockIdx.x * 256 + threadIdx.x;
  int t = blockIdx.y;
  if (e >= NE_) return;
  int s, d;
  if (e < EG_) { const int* b = ed + (size_t)t * 2 * EG_; s = b[e]; d = b[EG_ + e]; }
  else { s = e - EG_; d = s; }
  float x = os[t * 2048 + s] + od[t * 2048 + d];
  x = x > 0.f ? x : 0.2f * x;
  float pe = expf(x);
  p[(size_t)t * NEP + e] = pe;
  atomicAdd(&den[t * 2048 + d], pe);
}

template<int H, int ACT>
__global__ void gat_agg_k(const int* __restrict__ rp, const int* __restrict__ ce,
                          const int* __restrict__ ed, const float* __restrict__ p,
                          const float* __restrict__ den, const float* __restrict__ h,
                          const float* __restrict__ bias, float* __restrict__ out) {
  int v = blockIdx.x, t = blockIdx.y, c = threadIdx.x;
  int g = t + 1;
  int beg = rp[g * 2048 + v], end = rp[g * 2048 + v + 1];
  const float* pp = p + (size_t)t * NEP;
  const float* hp = h + (size_t)t * NG * H;
  const int* edt = ed + (size_t)t * 2 * EG_;
  float acc = 0.f;
  for (int i = beg; i < end; ++i) {
    int e = ce[(size_t)g * NEP + i];
    int s = (e < EG_) ? edt[e] : e - EG_;
    acc += pp[e] * hp[(long)s * H + c];
  }
  float r = acc / den[t * 2048 + v] + bias[t * H + c];
  out[((long)t * NG + v) * H + c] = (ACT == 1) ? fmaxf(r, 0.f) : sigm(r);
}

// ---------------------------------------------------------------------------
// TA BatchNorm+sigmoid mask + multiply.  One block per column c.
// Reads transposed split-K partials ypT[z][H][ldy] (coalesced over rows).
// out[r,c] = xs[r,c] * sigmoid( (y-mu)/sqrt(var+eps)*g[c] + be[c] ),
// y[r] = sum_z ypT[z][c][r] + cb[r]
// ---------------------------------------------------------------------------
__global__ __launch_bounds__(256) void bn_mask_k(
    const float* __restrict__ ypT, int SK, int H, int ldy,
    const float* __restrict__ cb, const float* __restrict__ gw,
    const float* __restrict__ bw, const float* __restrict__ xs,
    float* __restrict__ out) {
  int c = blockIdx.x, tid = threadIdx.x;
  __shared__ float ys[NG];
  __shared__ float red[256];
  float sum = 0.f;
  for (int r = tid; r < NG; r += 256) {
    float y = cb[r];
    for (int s = 0; s < SK; ++s) y += ypT[((long)s * H + c) * ldy + r];
    ys[r] = y; sum += y;
  }
  red[tid] = sum; __syncthreads();
  for (int s2 = 128; s2 > 0; s2 >>= 1) { if (tid < s2) red[tid] += red[tid + s2]; __syncthreads(); }
  float mu = red[0] * (1.f / NG); __syncthreads();
  float sq = 0.f;
  for (int r = tid; r < NG; r += 256) { float d = ys[r] - mu; sq += d * d; }
  red[tid] = sq; __syncthreads();
  for (int s2 = 128; s2 > 0; s2 >>= 1) { if (tid < s2) red[tid] += red[tid + s2]; __syncthreads(); }
  float rstd = 1.f / sqrtf(red[0] * (1.f / NG) + 1e-5f);
  float gc = gw[c], bc = bw[c];
  for (int r = tid; r < NG; r += 256) {
    float m = sigm((ys[r] - mu) * rstd * gc + bc);
    out[(long)r * H + c] = xs[(long)r * H + c] * m;
  }
}

// ---------------------------------------------------------------------------
// losses
// ---------------------------------------------------------------------------
__global__ __launch_bounds__(256) void loss_g_k(const float* __restrict__ xg,
                                                const float* __restrict__ rec,
                                                float* __restrict__ scal) {
  int idx = blockIdx.x * 256 + threadIdx.x;
  float m = 0.f, kl = 0.f;
  if (idx < NG * 8) {
    float a = xg[idx], b = rec[idx];
    float d = a - b; m = d * d;
    kl = b * (logf(b) - a);
  }
  m = blk_red256(m); kl = blk_red256(kl);
  if (threadIdx.x == 0) { atomicAdd(scal + 0, m); atomicAdd(scal + 1, kl); }
}

__global__ __launch_bounds__(256) void loss_d_k(const float* __restrict__ xd,
                                                const float* __restrict__ rec,
                                                float* __restrict__ scal) {
  const float* a = xd + (size_t)6 * NG * 256;
  const float* b = rec + (size_t)6 * NG * 256;
  float m = 0.f, kl = 0.f;
  for (int i = blockIdx.x * 256 + threadIdx.x; i < NG * 256; i += gridDim.x * 256) {
    float av = a[i], bv = b[i];
    float d = av - bv; m += d * d;
    kl += bv * (logf(bv) - av);
  }
  m = blk_red256(m); kl = blk_red256(kl);
  if (threadIdx.x == 0) { atomicAdd(scal + 2, m); atomicAdd(scal + 3, kl); }
}

__global__ __launch_bounds__(256) void loss_t_k(const float* __restrict__ rec,
                                                float* __restrict__ scal) {
  int i = blockIdx.y;
  const float* a = rec + (size_t)i * NG * 256;
  const float* b = rec + (size_t)(i + 1) * NG * 256;
  float kl = 0.f;
  for (int e = blockIdx.x * 256 + threadIdx.x; e < NG * 256; e += gridDim.x * 256)
    kl += b[e] * (logf(b[e]) - a[e]);
  kl = blk_red256(kl);
  if (threadIdx.x == 0) atomicAdd(scal + 4, kl);
}

__global__ void fin_k(const float* __restrict__ scal, float* __restrict__ out) {
  float lg = scal[0] / (NG * 8.f) + scal[1] / (float)NG;
  float ld = scal[2] / (NG * 256.f) + scal[3] / (float)NG;
  float lt = (scal[4] / (float)NG) * (1.f / 7.f);
  out[NG * 96] = lg + ld + 0.5f * lt;
}

__global__ __launch_bounds__(256) void concat_k(const float* __restrict__ xgenc,
                                                const float* __restrict__ xdenc,
                                                float* __restrict__ out) {
  int idx = blockIdx.x * 256 + threadIdx.x;
  if (idx >= NG * 96) return;
  int v = idx / 96, c = idx % 96;
  out[idx] = (c < 32) ? xgenc[v * 32 + c]
                      : xdenc[((size_t)6 * NG + v) * 64 + (c - 32)];
}

// ---------------------------------------------------------------------------
// launch
// ---------------------------------------------------------------------------
extern "C" void kernel_launch(void* const* d_in, const int* in_sizes, int n_in,
                              void* d_out, int out_size, void* d_ws, size_t ws_size,
                              hipStream_t stream) {
  const float* x_g    = (const float*)d_in[0];
  const int*   eg     = (const int*)d_in[1];
  const float* wg     = (const float*)d_in[2];
  const float* x_d    = (const float*)d_in[3];
  const int*   ed     = (const int*)d_in[4];
  const float* gcnW0  = (const float*)d_in[5];
  const float* gcnb0  = (const float*)d_in[6];
  const float* gcnW1  = (const float*)d_in[7];
  const float* gcnb1  = (const float*)d_in[8];
  const float* dgW0   = (const float*)d_in[9];
  const float* dgb0   = (const float*)d_in[10];
  const float* dgW1   = (const float*)d_in[11];
  const float* dgb1   = (const float*)d_in[12];
  const float* gatW0  = (const float*)d_in[13];
  const float* gatb0  = (const float*)d_in[14];
  const float* gatas0 = (const float*)d_in[15];
  const float* gatad0 = (const float*)d_in[16];
  const float* gatW1  = (const float*)d_in[17];
  const float* gatb1  = (const float*)d_in[18];
  const float* gatas1 = (const float*)d_in[19];
  const float* gatad1 = (const float*)d_in[20];
  const float* tacw0  = (const float*)d_in[21];
  const float* tacb0  = (const float*)d_in[22];
  const float* tag0   = (const float*)d_in[23];
  const float* tabe0  = (const float*)d_in[24];
  const float* tacw1  = (const float*)d_in[25];
  const float* tacb1  = (const float*)d_in[26];
  const float* tag1   = (const float*)d_in[27];
  const float* tabe1  = (const float*)d_in[28];
  const float* ddW0   = (const float*)d_in[29];
  const float* ddb0   = (const float*)d_in[30];
  const float* ddW1   = (const float*)d_in[31];
  const float* ddb1   = (const float*)d_in[32];
  float* out = (float*)d_out;

  float* ws = (float*)d_ws;
  size_t off = 0;
  auto alloc = [&](size_t n) { size_t o = off; off += n; return o; };
  // --- zeroed region (one memset) ---
  size_t o_cnt  = alloc(8 * 2048);       // int
  size_t o_cur  = alloc(8 * 2048);       // int
  size_t o_deg  = alloc(2048);
  size_t o_den0 = alloc(7 * 2048);
  size_t o_den1 = alloc(7 * 2048);
  size_t o_scal = alloc(16);
  size_t zero_words = off;
  // --- rest ---
  size_t o_rp    = alloc(8 * 2048);      // int
  size_t o_ce    = alloc((size_t)8 * NEP); // int
  size_t o_dinv  = alloc(2048);
  size_t o_hg0   = alloc(NG * 64);
  size_t o_xh    = alloc(NG * 64);
  size_t o_hg1   = alloc(NG * 32);
  size_t o_xgenc = alloc(NG * 32);
  size_t o_dgh   = alloc(NG * 64);
  size_t o_xgrec = alloc(NG * 8);
  size_t o_hd0   = alloc((size_t)7 * NG * 128);   // reused as dh
  size_t o_as0   = alloc(7 * 2048);
  size_t o_ad0   = alloc(7 * 2048);
  size_t o_p0    = alloc((size_t)7 * NEP);
  size_t o_xs0   = alloc((size_t)7 * NG * 128);
  size_t o_temps = alloc((size_t)7 * NG * 128);
  size_t o_ypT   = alloc((size_t)16 * 128 * 2048); // reused as xd_rec
  size_t o_hd1   = alloc((size_t)7 * NG * 64);
  size_t o_as1   = alloc(7 * 2048);
  size_t o_ad1   = alloc(7 * 2048);
  size_t o_p1    = alloc((size_t)7 * NEP);
  size_t o_xs1   = alloc((size_t)7 * NG * 64);
  size_t o_xdenc = alloc((size_t)7 * NG * 64);
  (void)ws_size; (void)in_sizes; (void)n_in; (void)out_size;

  int*   cnt   = (int*)(ws + o_cnt);
  int*   cur   = (int*)(ws + o_cur);
  int*   rp    = (int*)(ws + o_rp);
  int*   ce    = (int*)(ws + o_ce);
  float* deg   = ws + o_deg;
  float* dinv  = ws + o_dinv;
  float* den0  = ws + o_den0;
  float* den1  = ws + o_den1;
  float* scal  = ws + o_scal;
  float* hg0   = ws + o_hg0;
  float* xh    = ws + o_xh;
  float* hg1   = ws + o_hg1;
  float* xgenc = ws + o_xgenc;
  float* dgh   = ws + o_dgh;
  float* xgrec = ws + o_xgrec;
  float* hd0   = ws + o_hd0;
  float* as0   = ws + o_as0;
  float* ad0   = ws + o_ad0;
  float* p0    = ws + o_p0;
  float* xs0   = ws + o_xs0;
  float* temps = ws + o_temps;
  float* ypT   = ws + o_ypT;
  float* hd1   = ws + o_hd1;
  float* as1   = ws + o_as1;
  float* ad1   = ws + o_ad1;
  float* p1    = ws + o_p1;
  float* xs1   = ws + o_xs1;
  float* xdenc = ws + o_xdenc;
  float* dh    = hd0;   // reuse
  float* xdrec = ypT;   // reuse

  hipMemsetAsync(d_ws, 0, zero_words * 4, stream);

  dim3 b256(256);
  const int EB = (NE_ + 255) / 256; // 508

  // ---- CSR for all 8 graphs ----
  csr_count_k<<<dim3(EB, 8), b256, 0, stream>>>(eg, ed, cnt);
  csr_scan_k<<<8, b256, 0, stream>>>(cnt, rp);
  csr_fill_k<<<dim3(EB, 8), b256, 0, stream>>>(eg, ed, rp, cur, ce);
  deg_k<<<EB, b256, 0, stream>>>(eg, wg, deg);
  dinv_k<<<8, b256, 0, stream>>>(deg, dinv);

  // ---- GCN encoder ----
  gemm_k<64, 4, true, false><<<dim3(16, 1, 1), b256, 0, stream>>>(
      x_g, 0, gcnW0, 0, nullptr, 0, hg0, 0, NG, 64, 8, 0, 0, 0);
  gcn_agg_k<<<NG, 64, 0, stream>>>(rp, ce, eg, wg, dinv, hg0, gcnb0, xh, 64, 1);
  gemm_k<64, 4, true, false><<<dim3(16, 1, 1), b256, 0, stream>>>(
      xh, 0, gcnW1, 0, nullptr, 0, hg1, 0, NG, 32, 64, 0, 0, 0);
  gcn_agg_k<<<NG, 64, 0, stream>>>(rp, ce, eg, wg, dinv, hg1, gcnb1, xgenc, 32, 2);

  // ---- Decoder_G + loss_g ----
  gemm_k<64, 4, true, false><<<dim3(16, 1, 1), b256, 0, stream>>>(
      xgenc, 0, dgW0, 0, dgb0, 0, dgh, 0, NG, 64, 32, 1, 0, 0);
  gemm_k<64, 4, true, false><<<dim3(16, 1, 1), b256, 0, stream>>>(
      dgh, 0, dgW1, 0, dgb1, 0, xgrec, 0, NG, 8, 64, 2, 0, 0);
  loss_g_k<<<(NG * 8 + 255) / 256, b256, 0, stream>>>(x_g, xgrec, scal);

  // ---- GAT layer 0 (batched over 7 t) ----
  gemm_k<128, 8, true, false><<<dim3(16, 1, 7), b256, 0, stream>>>(
      x_d, (long)NG * 256, gatW0, (long)128 * 256, nullptr, 0, hd0, (long)NG * 128,
      NG, 128, 256, 0, 0, 0);
  att_scores_k<128><<<dim3(NG, 7), 64, 0, stream>>>(hd0, gatas0, gatad0, as0, ad0);
  edge_p_k<<<dim3(EB, 7), b256, 0, stream>>>(ed, as0, ad0, p0, den0);
  gat_agg_k<128, 1><<<dim3(NG, 7), 128, 0, stream>>>(rp, ce, ed, p0, den0, hd0, gatb0, xs0);

  // ---- TA chain 1 (sequential) -> temps ----
  hipMemcpyAsync(temps, xs0, (size_t)NG * 128 * 4, hipMemcpyDeviceToDevice, stream);
  for (int j = 1; j <= 6; ++j) {
    gemm_k<128, 8, false, true><<<dim3(16, 1, 16), b256, 0, stream>>>(
        tacw0 + (size_t)(j - 1) * NG * NG, 0, temps + (size_t)(j - 1) * NG * 128, 0,
        nullptr, 0, ypT, 0, NG, 128, NG, 0, 125, 2048);
    bn_mask_k<<<128, b256, 0, stream>>>(ypT, 16, 128, 2048,
        tacb0 + (size_t)(j - 1) * NG, tag0 + (j - 1) * 128, tabe0 + (j - 1) * 128,
        xs0 + (size_t)j * NG * 128, temps + (size_t)j * NG * 128);
  }

  // ---- GAT layer 1 (batched) ----
  gemm_k<64, 4, true, false><<<dim3(16, 1, 7), b256, 0, stream>>>(
      temps, (long)NG * 128, gatW1, (long)64 * 128, nullptr, 0, hd1, (long)NG * 64,
      NG, 64, 128, 0, 0, 0);
  att_scores_k<64><<<dim3(NG, 7), 64, 0, stream>>>(hd1, gatas1, gatad1, as1, ad1);
  edge_p_k<<<dim3(EB, 7), b256, 0, stream>>>(ed, as1, ad1, p1, den1);
  gat_agg_k<64, 2><<<dim3(NG, 7), 64, 0, stream>>>(rp, ce, ed, p1, den1, hd1, gatb1, xs1);

  // ---- TA chain 2 (sequential) -> xd_enc ----
  hipMemcpyAsync(xdenc, xs1, (size_t)NG * 64 * 4, hipMemcpyDeviceToDevice, stream);
  for (int j = 0; j < 6; ++j) {
    gemm_k<64, 4, false, true><<<dim3(16, 1, 16), b256, 0, stream>>>(
        tacw1 + (size_t)j * NG * NG, 0, xdenc + (size_t)j * NG * 64, 0,
        nullptr, 0, ypT, 0, NG, 64, NG, 0, 125, 2048);
    bn_mask_k<<<64, b256, 0, stream>>>(ypT, 16, 64, 2048,
        tacb1 + (size_t)j * NG, tag1 + j * 64, tabe1 + j * 64,
        xs1 + (size_t)(j + 1) * NG * 64, xdenc + (size_t)(j + 1) * NG * 64);
  }

  // ---- Decoder_D (batched) ----
  gemm_k<128, 8, true, false><<<dim3(16, 1, 7), b256, 0, stream>>>(
      xdenc, (long)NG * 64, ddW0, (long)128 * 64, ddb0, 128, dh, (long)NG * 128,
      NG, 128, 64, 1, 0, 0);
  gemm_k<128, 8, true, false><<<dim3(16, 2, 7), b256, 0, stream>>>(
      dh, (long)NG * 128, ddW1, (long)256 * 128, ddb1, 256, xdrec, (long)NG * 256,
      NG, 256, 128, 2, 0, 0);

  // ---- losses + output ----
  loss_d_k<<<512, b256, 0, stream>>>(x_d, xdrec, scal);
  loss_t_k<<<dim3(128, 6), b256, 0, stream>>>(xdrec, scal);
  concat_k<<<(NG * 96 + 255) / 256, b256, 0, stream>>>(xgenc, xdenc, out);
  fin_k<<<1, 1, 0, stream>>>(scal, out);
}

// Round 2
// 1708.171 us; speedup vs baseline: 1.4481x; 1.4481x over previous
//
#include <hip/hip_runtime.h>
#include <math.h>

#define NG   2000
#define EG_  128000
#define NE_  130000      // EG_ + NG (edges incl. self-loops)
#define NEP  130048      // padded
#define T1_  7
#define SK_TA 8          // split-K chunks for TA GEMM (K padded to 2048, KC=256)

typedef __attribute__((ext_vector_type(8))) short s16x8;
typedef __attribute__((ext_vector_type(4))) float f32x4;
#define MFMA16(a, b, c) __builtin_amdgcn_mfma_f32_16x16x32_bf16(a, b, c, 0, 0, 0)

// ---------------------------------------------------------------------------
// helpers
// ---------------------------------------------------------------------------
__device__ __forceinline__ void edge_sd(int g, int e, const int* __restrict__ eg,
                                        const int* __restrict__ ed, int& s, int& d) {
  if (e >= EG_) { s = e - EG_; d = s; return; }
  const int* b = (g == 0) ? eg : (ed + (size_t)(g - 1) * 2 * EG_);
  s = b[e]; d = b[EG_ + e];
}

__device__ __forceinline__ float blk_red256(float v) {
  __shared__ float red[256];
  int tid = threadIdx.x;
  red[tid] = v; __syncthreads();
  for (int s = 128; s > 0; s >>= 1) { if (tid < s) red[tid] += red[tid + s]; __syncthreads(); }
  float r = red[0]; __syncthreads();
  return r;
}

__device__ __forceinline__ float sigm(float x) { return 1.f / (1.f + expf(-x)); }

// round-to-nearest-even fp32 -> bf16
__device__ __forceinline__ ushort f2bf(float f) {
  union { float f; unsigned u; } c; c.f = f;
  unsigned u = c.u;
  unsigned r = (u + 0x7FFFu + ((u >> 16) & 1u)) >> 16;
  return (ushort)r;
}
__device__ __forceinline__ float bf2f(ushort h) {
  union { unsigned u; float f; } c; c.u = ((unsigned)h) << 16;
  return c.f;
}

// ---------------------------------------------------------------------------
// CSR build (8 graphs: g=0 gene, g=1..7 drug t=g-1)
// ---------------------------------------------------------------------------
__global__ __launch_bounds__(256) void csr_count_k(const int* __restrict__ eg,
                                                   const int* __restrict__ ed,
                                                   int* __restrict__ cnt) {
  int e = blockIdx.x * 256 + threadIdx.x;
  int g = blockIdx.y;
  if (e >= NE_) return;
  int s, d; edge_sd(g, e, eg, ed, s, d);
  atomicAdd(&cnt[g * 2048 + d], 1);
}

__global__ __launch_bounds__(256) void csr_scan_k(const int* __restrict__ cnt,
                                                  int* __restrict__ rp) {
  int g = blockIdx.x, tid = threadIdx.x;
  const int* c = cnt + g * 2048;
  int* r = rp + g * 2048;
  int loc[8]; int s = 0;
  int base = tid * 8;
#pragma unroll
  for (int i = 0; i < 8; ++i) { loc[i] = s; int idx = base + i; s += (idx < NG) ? c[idx] : 0; }
  __shared__ int ps[256];
  ps[tid] = s; __syncthreads();
  for (int st = 1; st < 256; st <<= 1) {
    int v = (tid >= st) ? ps[tid - st] : 0; __syncthreads();
    ps[tid] += v; __syncthreads();
  }
  int excl = ps[tid] - s;
#pragma unroll
  for (int i = 0; i < 8; ++i) { int idx = base + i; if (idx < NG) r[idx] = excl + loc[i]; }
  if (tid == 255) r[NG] = ps[255];
}

__global__ __launch_bounds__(256) void csr_fill_k(const int* __restrict__ eg,
                                                  const int* __restrict__ ed,
                                                  const int* __restrict__ rp,
                                                  int* __restrict__ cur,
                                                  int* __restrict__ ce) {
  int e = blockIdx.x * 256 + threadIdx.x;
  int g = blockIdx.y;
  if (e >= NE_) return;
  int s, d; edge_sd(g, e, eg, ed, s, d);
  int pos = rp[g * 2048 + d] + atomicAdd(&cur[g * 2048 + d], 1);
  ce[(size_t)g * NEP + pos] = e;
}

// ---------------------------------------------------------------------------
// GCN degree / dinv
// ---------------------------------------------------------------------------
__global__ __launch_bounds__(256) void deg_k(const int* __restrict__ eg,
                                             const float* __restrict__ w,
                                             float* __restrict__ deg) {
  int e = blockIdx.x * 256 + threadIdx.x;
  if (e >= NE_) return;
  int d; float wv;
  if (e < EG_) { d = eg[EG_ + e]; wv = w[e]; } else { d = e - EG_; wv = 2.f; }
  atomicAdd(&deg[d], wv);
}

__global__ __launch_bounds__(256) void dinv_k(const float* __restrict__ deg,
                                              float* __restrict__ dinv) {
  int v = blockIdx.x * 256 + threadIdx.x;
  if (v >= NG) return;
  float dg = deg[v];
  dinv[v] = dg > 0.f ? 1.f / sqrtf(dg) : 0.f;
}

// ---------------------------------------------------------------------------
// fp32 tiled GEMM (kept for the tiny gene-side matmuls, K<=64, N<=64)
// C[M,N] = A[M,K] @ W[N,K]^T ; bias+act epilogue.
// ---------------------------------------------------------------------------
template<int BN, int TN>
__global__ __launch_bounds__(256) void gemm_k(
    const float* __restrict__ A,
    const float* __restrict__ Bm,
    const float* __restrict__ bias,
    float* __restrict__ C,
    int M, int N, int K, int act) {
  constexpr int BM = 128, BK = 32, TM = 8;
  __shared__ float As[BK][BM + 1];
  __shared__ float Bs[BK][BN + 1];
  int tid = threadIdx.x;
  int tc = tid & 15, tr = tid >> 4;
  int m0 = blockIdx.x * BM, n0 = blockIdx.y * BN;
  float acc[TM][TN] = {};
  for (int k0 = 0; k0 < K; k0 += BK) {
    __syncthreads();
    for (int i = tid; i < BM * BK; i += 256) {
      int m = i >> 5, k = i & 31;
      int gm = m0 + m, gk = k0 + k;
      As[k][m] = (gm < M && gk < K) ? A[(long)gm * K + gk] : 0.f;
    }
    for (int i = tid; i < BN * BK; i += 256) {
      int n = i >> 5, k = i & 31;
      int gn = n0 + n, gk = k0 + k;
      Bs[k][n] = (gn < N && gk < K) ? Bm[(long)gn * K + gk] : 0.f;
    }
    __syncthreads();
#pragma unroll
    for (int kk = 0; kk < BK; ++kk) {
      float a[TM], b[TN];
#pragma unroll
      for (int i = 0; i < TM; ++i) a[i] = As[kk][tr * TM + i];
#pragma unroll
      for (int j = 0; j < TN; ++j) b[j] = Bs[kk][tc * TN + j];
#pragma unroll
      for (int i = 0; i < TM; ++i)
#pragma unroll
        for (int j = 0; j < TN; ++j) acc[i][j] = fmaf(a[i], b[j], acc[i][j]);
    }
  }
#pragma unroll
  for (int i = 0; i < TM; ++i) {
    int gm = m0 + tr * TM + i;
    if (gm >= M) continue;
#pragma unroll
    for (int j = 0; j < TN; ++j) {
      int gc = n0 + tc * TN + j;
      if (gc >= N) continue;
      float v = acc[i][j] + (bias ? bias[gc] : 0.f);
      if (act == 1) v = fmaxf(v, 0.f);
      else if (act == 2) v = sigm(v);
      C[(long)gm * N + gc] = v;
    }
  }
}

// ---------------------------------------------------------------------------
// TA GEMM (MFMA, split-bf16): ypT[z][H][2048] partial of W[2000,2000]@X[2000,H]
// X pre-split & transposed: xthi/xtlo [H][2048] bf16, rows>=NG zero-padded.
// W split in-kernel. 3-term product: hi*hi + lo*hi + hi*lo (err ~2^-18).
// grid (16, 1, SK_TA), 256 thr (4 waves); BM=128, BK=64, KC=256.
// ---------------------------------------------------------------------------
template<int H>
__global__ __launch_bounds__(256) void ta_gemm_k(
    const float* __restrict__ W,
    const ushort* __restrict__ xthi, const ushort* __restrict__ xtlo,
    float* __restrict__ ypT) {
  constexpr int NB = H / 16;
  __shared__ ushort Whi[128 * 64], Wlo[128 * 64];
  __shared__ ushort Xhi[H * 64], Xlo[H * 64];
  int tid = threadIdx.x;
  int m0 = blockIdx.x * 128;
  int z = blockIdx.z;
  int kbeg = z * 256;
  int w = tid >> 6, lane = tid & 63;
  int lrow = lane & 15, lk8 = (lane >> 4) * 8;
  f32x4 acc[2][NB] = {};
  for (int k0 = kbeg; k0 < kbeg + 256; k0 += 64) {
    // ---- stage W tile [128][64] fp32 -> split bf16, XOR-swizzled ----
#pragma unroll
    for (int it = 0; it < 8; ++it) {
      int idx4 = tid + it * 256;
      int row = idx4 >> 4, kq = (idx4 & 15) << 2;
      int gm = m0 + row, gk = k0 + kq;
      float4 v = make_float4(0.f, 0.f, 0.f, 0.f);
      if (gm < NG && gk < NG) v = *(const float4*)(W + (size_t)gm * NG + gk);
      ushort h0 = f2bf(v.x), h1 = f2bf(v.y), h2 = f2bf(v.z), h3 = f2bf(v.w);
      int li = row * 64 + (kq ^ ((row & 7) << 3));
      *(ushort4*)(Whi + li) = make_ushort4(h0, h1, h2, h3);
      *(ushort4*)(Wlo + li) = make_ushort4(f2bf(v.x - bf2f(h0)), f2bf(v.y - bf2f(h1)),
                                           f2bf(v.z - bf2f(h2)), f2bf(v.w - bf2f(h3)));
    }
    // ---- stage X tile [H][64] bf16 (pre-split), XOR-swizzled ----
#pragma unroll
    for (int it = 0; it < H / 32; ++it) {
      int idx8 = tid + it * 256;
      int col = idx8 >> 3, kq = (idx8 & 7) << 3;
      size_t gsrc = ((size_t)col << 11) + k0 + kq;
      int li = col * 64 + (kq ^ ((col & 7) << 3));
      *(uint4*)(Xhi + li) = *(const uint4*)(xthi + gsrc);
      *(uint4*)(Xlo + li) = *(const uint4*)(xtlo + gsrc);
    }
    __syncthreads();
#pragma unroll
    for (int kk = 0; kk < 64; kk += 32) {
      s16x8 ah[2], al[2];
#pragma unroll
      for (int mt = 0; mt < 2; ++mt) {
        int row = w * 32 + mt * 16 + lrow;
        int ki = kk + lk8;
        int li = row * 64 + (ki ^ ((row & 7) << 3));
        ah[mt] = *(const s16x8*)(Whi + li);
        al[mt] = *(const s16x8*)(Wlo + li);
      }
#pragma unroll
      for (int nt = 0; nt < NB; ++nt) {
        int col = nt * 16 + lrow;
        int ki = kk + lk8;
        int li = col * 64 + (ki ^ ((col & 7) << 3));
        s16x8 bh = *(const s16x8*)(Xhi + li);
        s16x8 bl = *(const s16x8*)(Xlo + li);
#pragma unroll
        for (int mt = 0; mt < 2; ++mt) {
          acc[mt][nt] = MFMA16(ah[mt], bh, acc[mt][nt]);
          acc[mt][nt] = MFMA16(al[mt], bh, acc[mt][nt]);
          acc[mt][nt] = MFMA16(ah[mt], bl, acc[mt][nt]);
        }
      }
    }
    __syncthreads();
  }
  // ---- epilogue: transposed split-K partial store ----
  int rb0 = m0 + w * 32 + (lane >> 4) * 4;
#pragma unroll
  for (int mt = 0; mt < 2; ++mt) {
    int rbase = rb0 + mt * 16;
#pragma unroll
    for (int nt = 0; nt < NB; ++nt) {
      int c = nt * 16 + lrow;
      float* dst = ypT + (((size_t)z * H + c) << 11) + rbase;
      if (rbase + 3 < NG) *(f32x4*)dst = acc[mt][nt];
      else {
#pragma unroll
        for (int i = 0; i < 4; ++i) if (rbase + i < NG) dst[i] = acc[mt][nt][i];
      }
    }
  }
}

// ---------------------------------------------------------------------------
// Batched projection GEMM (MFMA, split-bf16, both operands split in-kernel):
// C[z][M,N] = A[z][M,K] @ W[z][N,K]^T + bias, act. K % 64 == 0, N % BN == 0.
// grid (ceil(M/128), N/BN, Z), 256 thr.
// ---------------------------------------------------------------------------
template<int BN>
__global__ __launch_bounds__(256) void proj_gemm_k(
    const float* __restrict__ A, long sA,
    const float* __restrict__ Wt, long sW,
    const float* __restrict__ bias, int sBias,
    float* __restrict__ C, long sC,
    int M, int N, int K, int act) {
  constexpr int NB = BN / 16;
  __shared__ ushort Ahi[128 * 64], Alo[128 * 64];
  __shared__ ushort Bhi[BN * 64], Blo[BN * 64];
  int tid = threadIdx.x;
  int m0 = blockIdx.x * 128, n0 = blockIdx.y * BN;
  int z = blockIdx.z;
  const float* Ap = A + (size_t)z * sA;
  const float* Wp = Wt + (size_t)z * sW;
  int w = tid >> 6, lane = tid & 63;
  int lrow = lane & 15, lk8 = (lane >> 4) * 8;
  f32x4 acc[2][NB] = {};
  for (int k0 = 0; k0 < K; k0 += 64) {
#pragma unroll
    for (int it = 0; it < 8; ++it) {
      int idx4 = tid + it * 256;
      int row = idx4 >> 4, kq = (idx4 & 15) << 2;
      int gm = m0 + row;
      float4 v = make_float4(0.f, 0.f, 0.f, 0.f);
      if (gm < M) v = *(const float4*)(Ap + (size_t)gm * K + k0 + kq);
      ushort h0 = f2bf(v.x), h1 = f2bf(v.y), h2 = f2bf(v.z), h3 = f2bf(v.w);
      int li = row * 64 + (kq ^ ((row & 7) << 3));
      *(ushort4*)(Ahi + li) = make_ushort4(h0, h1, h2, h3);
      *(ushort4*)(Alo + li) = make_ushort4(f2bf(v.x - bf2f(h0)), f2bf(v.y - bf2f(h1)),
                                           f2bf(v.z - bf2f(h2)), f2bf(v.w - bf2f(h3)));
    }
#pragma unroll
    for (int it = 0; it < BN / 16; ++it) {
      int idx4 = tid + it * 256;
      int row = idx4 >> 4, kq = (idx4 & 15) << 2;
      float4 v = *(const float4*)(Wp + (size_t)(n0 + row) * K + k0 + kq);
      ushort h0 = f2bf(v.x), h1 = f2bf(v.y), h2 = f2bf(v.z), h3 = f2bf(v.w);
      int li = row * 64 + (kq ^ ((row & 7) << 3));
      *(ushort4*)(Bhi + li) = make_ushort4(h0, h1, h2, h3);
      *(ushort4*)(Blo + li) = make_ushort4(f2bf(v.x - bf2f(h0)), f2bf(v.y - bf2f(h1)),
                                           f2bf(v.z - bf2f(h2)), f2bf(v.w - bf2f(h3)));
    }
    __syncthreads();
#pragma unroll
    for (int kk = 0; kk < 64; kk += 32) {
      s16x8 ah[2], al[2];
#pragma unroll
      for (int mt = 0; mt < 2; ++mt) {
        int row = w * 32 + mt * 16 + lrow;
        int ki = kk + lk8;
        int li = row * 64 + (ki ^ ((row & 7) << 3));
        ah[mt] = *(const s16x8*)(Ahi + li);
        al[mt] = *(const s16x8*)(Alo + li);
      }
#pragma unroll
      for (int nt = 0; nt < NB; ++nt) {
        int col = nt * 16 + lrow;
        int ki = kk + lk8;
        int li = col * 64 + (ki ^ ((col & 7) << 3));
        s16x8 bh = *(const s16x8*)(Bhi + li);
        s16x8 bl = *(const s16x8*)(Blo + li);
#pragma unroll
        for (int mt = 0; mt < 2; ++mt) {
          acc[mt][nt] = MFMA16(ah[mt], bh, acc[mt][nt]);
          acc[mt][nt] = MFMA16(al[mt], bh, acc[mt][nt]);
          acc[mt][nt] = MFMA16(ah[mt], bl, acc[mt][nt]);
        }
      }
    }
    __syncthreads();
  }
  const float* bp = bias ? bias + (size_t)z * sBias : nullptr;
  float* Cp = C + (size_t)z * sC;
  int rb0 = m0 + w * 32 + (lane >> 4) * 4;
#pragma unroll
  for (int mt = 0; mt < 2; ++mt) {
    int rbase = rb0 + mt * 16;
#pragma unroll
    for (int nt = 0; nt < NB; ++nt) {
      int c = n0 + nt * 16 + lrow;
      float bv = bp ? bp[c] : 0.f;
#pragma unroll
      for (int i = 0; i < 4; ++i) {
        int r = rbase + i;
        if (r < M) {
          float v = acc[mt][nt][i] + bv;
          if (act == 1) v = fmaxf(v, 0.f);
          else if (act == 2) v = sigm(v);
          Cp[(size_t)r * N + c] = v;
        }
      }
    }
  }
}

// ---------------------------------------------------------------------------
// split+transpose: in[NG][H] fp32 -> hi/lo [H][2048] bf16 (zero-padded rows)
// ---------------------------------------------------------------------------
template<int H>
__global__ __launch_bounds__(256) void split_t_k(const float* __restrict__ in,
                                                 ushort* __restrict__ hi,
                                                 ushort* __restrict__ lo) {
  int c = blockIdx.x, tid = threadIdx.x;
  for (int r = tid; r < 2048; r += 256) {
    float v = (r < NG) ? in[(size_t)r * H + c] : 0.f;
    ushort h = f2bf(v);
    hi[(size_t)c * 2048 + r] = h;
    lo[(size_t)c * 2048 + r] = f2bf(v - bf2f(h));
  }
}

// ---------------------------------------------------------------------------
// GCN aggregation
// ---------------------------------------------------------------------------
__global__ void gcn_agg_k(const int* __restrict__ rp, const int* __restrict__ ce,
                          const int* __restrict__ eg, const float* __restrict__ w,
                          const float* __restrict__ dinv, const float* __restrict__ h,
                          const float* __restrict__ bias, float* __restrict__ out,
                          int N, int act) {
  int v = blockIdx.x, c = threadIdx.x;
  if (c >= N) return;
  int beg = rp[v], end = rp[v + 1];
  float acc = 0.f;
  for (int i = beg; i < end; ++i) {
    int e = ce[i];
    int s; float wv;
    if (e < EG_) { s = eg[e]; wv = w[e]; } else { s = e - EG_; wv = 2.f; }
    acc += wv * dinv[s] * h[(long)s * N + c];
  }
  float r = dinv[v] * acc + bias[c];
  out[(long)v * N + c] = (act == 1) ? fmaxf(r, 0.f) : sigm(r);
}

// ---------------------------------------------------------------------------
// GAT attention pieces
// ---------------------------------------------------------------------------
template<int H>
__global__ void att_scores_k(const float* __restrict__ h, const float* __restrict__ a_s,
                             const float* __restrict__ a_d, float* __restrict__ os,
                             float* __restrict__ od) {
  int v = blockIdx.x, t = blockIdx.y, l = threadIdx.x;
  const float* hp = h + ((long)t * NG + v) * H;
  const float* asp = a_s + t * H;
  const float* adp = a_d + t * H;
  float vs = 0.f, vd = 0.f;
  for (int c = l; c < H; c += 64) { float hv = hp[c]; vs += hv * asp[c]; vd += hv * adp[c]; }
  for (int o = 32; o; o >>= 1) { vs += __shfl_down(vs, o); vd += __shfl_down(vd, o); }
  if (l == 0) { os[t * 2048 + v] = vs; od[t * 2048 + v] = vd; }
}

__global__ __launch_bounds__(256) void edge_p_k(const int* __restrict__ ed,
                                                const float* __restrict__ os,
                                                const float* __restrict__ od,
                                                float* __restrict__ p,
                                                float* __restrict__ den) {
  int e = blockIdx.x * 256 + threadIdx.x;
  int t = blockIdx.y;
  if (e >= NE_) return;
  int s, d;
  if (e < EG_) { const int* b = ed + (size_t)t * 2 * EG_; s = b[e]; d = b[EG_ + e]; }
  else { s = e - EG_; d = s; }
  float x = os[t * 2048 + s] + od[t * 2048 + d];
  x = x > 0.f ? x : 0.2f * x;
  float pe = expf(x);
  p[(size_t)t * NEP + e] = pe;
  atomicAdd(&den[t * 2048 + d], pe);
}

template<int H, int ACT>
__global__ void gat_agg_k(const int* __restrict__ rp, const int* __restrict__ ce,
                          const int* __restrict__ ed, const float* __restrict__ p,
                          const float* __restrict__ den, const float* __restrict__ h,
                          const float* __restrict__ bias, float* __restrict__ out) {
  int v = blockIdx.x, t = blockIdx.y, c = threadIdx.x;
  int g = t + 1;
  int beg = rp[g * 2048 + v], end = rp[g * 2048 + v + 1];
  const float* pp = p + (size_t)t * NEP;
  const float* hp = h + (size_t)t * NG * H;
  const int* edt = ed + (size_t)t * 2 * EG_;
  float acc = 0.f;
  for (int i = beg; i < end; ++i) {
    int e = ce[(size_t)g * NEP + i];
    int s = (e < EG_) ? edt[e] : e - EG_;
    acc += pp[e] * hp[(long)s * H + c];
  }
  float r = acc / den[t * 2048 + v] + bias[t * H + c];
  out[((long)t * NG + v) * H + c] = (ACT == 1) ? fmaxf(r, 0.f) : sigm(r);
}

// ---------------------------------------------------------------------------
// TA BatchNorm+sigmoid mask + multiply; also emits split-bf16 transposed copy
// of the product for the next TA GEMM (xthi/xtlo nullable).
// ---------------------------------------------------------------------------
__global__ __launch_bounds__(256) void bn_mask_k(
    const float* __restrict__ ypT, int SK, int H,
    const float* __restrict__ cb, const float* __restrict__ gw,
    const float* __restrict__ bw, const float* __restrict__ xs,
    float* __restrict__ out, ushort* __restrict__ xthi, ushort* __restrict__ xtlo) {
  int c = blockIdx.x, tid = threadIdx.x;
  __shared__ float ys[NG];
  __shared__ float red[256];
  float sum = 0.f;
  for (int r = tid; r < NG; r += 256) {
    float y = cb[r];
    for (int s = 0; s < SK; ++s) y += ypT[(((size_t)s * H + c) << 11) + r];
    ys[r] = y; sum += y;
  }
  red[tid] = sum; __syncthreads();
  for (int s2 = 128; s2 > 0; s2 >>= 1) { if (tid < s2) red[tid] += red[tid + s2]; __syncthreads(); }
  float mu = red[0] * (1.f / NG); __syncthreads();
  float sq = 0.f;
  for (int r = tid; r < NG; r += 256) { float d = ys[r] - mu; sq += d * d; }
  red[tid] = sq; __syncthreads();
  for (int s2 = 128; s2 > 0; s2 >>= 1) { if (tid < s2) red[tid] += red[tid + s2]; __syncthreads(); }
  float rstd = 1.f / sqrtf(red[0] * (1.f / NG) + 1e-5f);
  float gc = gw[c], bc = bw[c];
  for (int r = tid; r < 2048; r += 256) {
    float val = 0.f;
    if (r < NG) {
      float m = sigm((ys[r] - mu) * rstd * gc + bc);
      val = xs[(size_t)r * H + c] * m;
      out[(size_t)r * H + c] = val;
    }
    if (xthi) {
      ushort h = f2bf(val);
      xthi[(size_t)c * 2048 + r] = h;
      xtlo[(size_t)c * 2048 + r] = f2bf(val - bf2f(h));
    }
  }
}

// ---------------------------------------------------------------------------
// losses
// ---------------------------------------------------------------------------
__global__ __launch_bounds__(256) void loss_g_k(const float* __restrict__ xg,
                                                const float* __restrict__ rec,
                                                float* __restrict__ scal) {
  int idx = blockIdx.x * 256 + threadIdx.x;
  float m = 0.f, kl = 0.f;
  if (idx < NG * 8) {
    float a = xg[idx], b = rec[idx];
    float d = a - b; m = d * d;
    kl = b * (logf(b) - a);
  }
  m = blk_red256(m); kl = blk_red256(kl);
  if (threadIdx.x == 0) { atomicAdd(scal + 0, m); atomicAdd(scal + 1, kl); }
}

__global__ __launch_bounds__(256) void loss_d_k(const float* __restrict__ xd,
                                                const float* __restrict__ rec,
                                                float* __restrict__ scal) {
  const float* a = xd + (size_t)6 * NG * 256;
  const float* b = rec + (size_t)6 * NG * 256;
  float m = 0.f, kl = 0.f;
  for (int i = blockIdx.x * 256 + threadIdx.x; i < NG * 256; i += gridDim.x * 256) {
    float av = a[i], bv = b[i];
    float d = av - bv; m += d * d;
    kl += bv * (logf(bv) - av);
  }
  m = blk_red256(m); kl = blk_red256(kl);
  if (threadIdx.x == 0) { atomicAdd(scal + 2, m); atomicAdd(scal + 3, kl); }
}

__global__ __launch_bounds__(256) void loss_t_k(const float* __restrict__ rec,
                                                float* __restrict__ scal) {
  int i = blockIdx.y;
  const float* a = rec + (size_t)i * NG * 256;
  const float* b = rec + (size_t)(i + 1) * NG * 256;
  float kl = 0.f;
  for (int e = blockIdx.x * 256 + threadIdx.x; e < NG * 256; e += gridDim.x * 256)
    kl += b[e] * (logf(b[e]) - a[e]);
  kl = blk_red256(kl);
  if (threadIdx.x == 0) atomicAdd(scal + 4, kl);
}

__global__ void fin_k(const float* __restrict__ scal, float* __restrict__ out) {
  float lg = scal[0] / (NG * 8.f) + scal[1] / (float)NG;
  float ld = scal[2] / (NG * 256.f) + scal[3] / (float)NG;
  float lt = (scal[4] / (float)NG) * (1.f / 7.f);
  out[NG * 96] = lg + ld + 0.5f * lt;
}

__global__ __launch_bounds__(256) void concat_k(const float* __restrict__ xgenc,
                                                const float* __restrict__ xdenc,
                                                float* __restrict__ out) {
  int idx = blockIdx.x * 256 + threadIdx.x;
  if (idx >= NG * 96) return;
  int v = idx / 96, c = idx % 96;
  out[idx] = (c < 32) ? xgenc[v * 32 + c]
                      : xdenc[((size_t)6 * NG + v) * 64 + (c - 32)];
}

// ---------------------------------------------------------------------------
// launch
// ---------------------------------------------------------------------------
extern "C" void kernel_launch(void* const* d_in, const int* in_sizes, int n_in,
                              void* d_out, int out_size, void* d_ws, size_t ws_size,
                              hipStream_t stream) {
  const float* x_g    = (const float*)d_in[0];
  const int*   eg     = (const int*)d_in[1];
  const float* wg     = (const float*)d_in[2];
  const float* x_d    = (const float*)d_in[3];
  const int*   ed     = (const int*)d_in[4];
  const float* gcnW0  = (const float*)d_in[5];
  const float* gcnb0  = (const float*)d_in[6];
  const float* gcnW1  = (const float*)d_in[7];
  const float* gcnb1  = (const float*)d_in[8];
  const float* dgW0   = (const float*)d_in[9];
  const float* dgb0   = (const float*)d_in[10];
  const float* dgW1   = (const float*)d_in[11];
  const float* dgb1   = (const float*)d_in[12];
  const float* gatW0  = (const float*)d_in[13];
  const float* gatb0  = (const float*)d_in[14];
  const float* gatas0 = (const float*)d_in[15];
  const float* gatad0 = (const float*)d_in[16];
  const float* gatW1  = (const float*)d_in[17];
  const float* gatb1  = (const float*)d_in[18];
  const float* gatas1 = (const float*)d_in[19];
  const float* gatad1 = (const float*)d_in[20];
  const float* tacw0  = (const float*)d_in[21];
  const float* tacb0  = (const float*)d_in[22];
  const float* tag0   = (const float*)d_in[23];
  const float* tabe0  = (const float*)d_in[24];
  const float* tacw1  = (const float*)d_in[25];
  const float* tacb1  = (const float*)d_in[26];
  const float* tag1   = (const float*)d_in[27];
  const float* tabe1  = (const float*)d_in[28];
  const float* ddW0   = (const float*)d_in[29];
  const float* ddb0   = (const float*)d_in[30];
  const float* ddW1   = (const float*)d_in[31];
  const float* ddb1   = (const float*)d_in[32];
  float* out = (float*)d_out;

  float* ws = (float*)d_ws;
  size_t off = 0;
  auto alloc = [&](size_t n) { size_t o = off; off += (n + 3) & ~(size_t)3; return o; };
  // --- zeroed region (one memset) ---
  size_t o_cnt  = alloc(8 * 2048);       // int
  size_t o_cur  = alloc(8 * 2048);       // int
  size_t o_deg  = alloc(2048);
  size_t o_den0 = alloc(7 * 2048);
  size_t o_den1 = alloc(7 * 2048);
  size_t o_scal = alloc(16);
  size_t zero_words = off;
  // --- rest ---
  size_t o_rp    = alloc(8 * 2048);      // int
  size_t o_ce    = alloc((size_t)8 * NEP); // int
  size_t o_dinv  = alloc(2048);
  size_t o_hg0   = alloc(NG * 64);
  size_t o_xh    = alloc(NG * 64);
  size_t o_hg1   = alloc(NG * 32);
  size_t o_xgenc = alloc(NG * 32);
  size_t o_dgh   = alloc(NG * 64);
  size_t o_xgrec = alloc(NG * 8);
  size_t o_hd0   = alloc((size_t)7 * NG * 128);   // reused as dh
  size_t o_as0   = alloc(7 * 2048);
  size_t o_ad0   = alloc(7 * 2048);
  size_t o_p0    = alloc((size_t)7 * NEP);
  size_t o_xs0   = alloc((size_t)7 * NG * 128);
  size_t o_temps = alloc((size_t)7 * NG * 128);
  size_t o_ypT   = alloc((size_t)16 * 128 * 2048); // reused as xd_rec
  size_t o_hd1   = alloc((size_t)7 * NG * 64);
  size_t o_as1   = alloc(7 * 2048);
  size_t o_ad1   = alloc(7 * 2048);
  size_t o_p1    = alloc((size_t)7 * NEP);
  size_t o_xs1   = alloc((size_t)7 * NG * 64);
  size_t o_xdenc = alloc((size_t)7 * NG * 64);
  size_t o_xt1hi = alloc((size_t)128 * 2048 / 2); // ushort planes (in float units)
  size_t o_xt1lo = alloc((size_t)128 * 2048 / 2);
  size_t o_xt2hi = alloc((size_t)64 * 2048 / 2);
  size_t o_xt2lo = alloc((size_t)64 * 2048 / 2);
  (void)ws_size; (void)in_sizes; (void)n_in; (void)out_size;

  int*   cnt   = (int*)(ws + o_cnt);
  int*   cur   = (int*)(ws + o_cur);
  int*   rp    = (int*)(ws + o_rp);
  int*   ce    = (int*)(ws + o_ce);
  float* deg   = ws + o_deg;
  float* dinv  = ws + o_dinv;
  float* den0  = ws + o_den0;
  float* den1  = ws + o_den1;
  float* scal  = ws + o_scal;
  float* hg0   = ws + o_hg0;
  float* xh    = ws + o_xh;
  float* hg1   = ws + o_hg1;
  float* xgenc = ws + o_xgenc;
  float* dgh   = ws + o_dgh;
  float* xgrec = ws + o_xgrec;
  float* hd0   = ws + o_hd0;
  float* as0   = ws + o_as0;
  float* ad0   = ws + o_ad0;
  float* p0    = ws + o_p0;
  float* xs0   = ws + o_xs0;
  float* temps = ws + o_temps;
  float* ypT   = ws + o_ypT;
  float* hd1   = ws + o_hd1;
  float* as1   = ws + o_as1;
  float* ad1   = ws + o_ad1;
  float* p1    = ws + o_p1;
  float* xs1   = ws + o_xs1;
  float* xdenc = ws + o_xdenc;
  ushort* xt1hi = (ushort*)(ws + o_xt1hi);
  ushort* xt1lo = (ushort*)(ws + o_xt1lo);
  ushort* xt2hi = (ushort*)(ws + o_xt2hi);
  ushort* xt2lo = (ushort*)(ws + o_xt2lo);
  float* dh    = hd0;   // reuse
  float* xdrec = ypT;   // reuse (14.3MB fits in the 16MB ypT region)

  hipMemsetAsync(d_ws, 0, zero_words * 4, stream);

  dim3 b256(256);
  const int EB = (NE_ + 255) / 256; // 508

  // ---- CSR for all 8 graphs ----
  csr_count_k<<<dim3(EB, 8), b256, 0, stream>>>(eg, ed, cnt);
  csr_scan_k<<<8, b256, 0, stream>>>(cnt, rp);
  csr_fill_k<<<dim3(EB, 8), b256, 0, stream>>>(eg, ed, rp, cur, ce);
  deg_k<<<EB, b256, 0, stream>>>(eg, wg, deg);
  dinv_k<<<8, b256, 0, stream>>>(deg, dinv);

  // ---- GCN encoder (tiny fp32 GEMMs) ----
  gemm_k<64, 4><<<dim3(16, 1, 1), b256, 0, stream>>>(x_g, gcnW0, nullptr, hg0, NG, 64, 8, 0);
  gcn_agg_k<<<NG, 64, 0, stream>>>(rp, ce, eg, wg, dinv, hg0, gcnb0, xh, 64, 1);
  gemm_k<64, 4><<<dim3(16, 1, 1), b256, 0, stream>>>(xh, gcnW1, nullptr, hg1, NG, 32, 64, 0);
  gcn_agg_k<<<NG, 64, 0, stream>>>(rp, ce, eg, wg, dinv, hg1, gcnb1, xgenc, 32, 2);

  // ---- Decoder_G + loss_g ----
  gemm_k<64, 4><<<dim3(16, 1, 1), b256, 0, stream>>>(xgenc, dgW0, dgb0, dgh, NG, 64, 32, 1);
  gemm_k<64, 4><<<dim3(16, 1, 1), b256, 0, stream>>>(dgh, dgW1, dgb1, xgrec, NG, 8, 64, 2);
  loss_g_k<<<(NG * 8 + 255) / 256, b256, 0, stream>>>(x_g, xgrec, scal);

  // ---- GAT layer 0 projection (MFMA, batched over 7 t) ----
  proj_gemm_k<128><<<dim3(16, 1, 7), b256, 0, stream>>>(
      x_d, (long)NG * 256, gatW0, (long)128 * 256, nullptr, 0, hd0, (long)NG * 128,
      NG, 128, 256, 0);
  att_scores_k<128><<<dim3(NG, 7), 64, 0, stream>>>(hd0, gatas0, gatad0, as0, ad0);
  edge_p_k<<<dim3(EB, 7), b256, 0, stream>>>(ed, as0, ad0, p0, den0);
  gat_agg_k<128, 1><<<dim3(NG, 7), 128, 0, stream>>>(rp, ce, ed, p0, den0, hd0, gatb0, xs0);

  // ---- TA chain 1 (sequential, H=128) ----
  hipMemcpyAsync(temps, xs0, (size_t)NG * 128 * 4, hipMemcpyDeviceToDevice, stream);
  split_t_k<128><<<128, b256, 0, stream>>>(xs0, xt1hi, xt1lo);
  for (int j = 1; j <= 6; ++j) {
    ta_gemm_k<128><<<dim3(16, 1, SK_TA), b256, 0, stream>>>(
        tacw0 + (size_t)(j - 1) * NG * NG, xt1hi, xt1lo, ypT);
    bool last = (j == 6);
    bn_mask_k<<<128, b256, 0, stream>>>(ypT, SK_TA, 128,
        tacb0 + (size_t)(j - 1) * NG, tag0 + (j - 1) * 128, tabe0 + (j - 1) * 128,
        xs0 + (size_t)j * NG * 128, temps + (size_t)j * NG * 128,
        last ? nullptr : xt1hi, last ? nullptr : xt1lo);
  }

  // ---- GAT layer 1 projection (MFMA, batched) ----
  proj_gemm_k<64><<<dim3(16, 1, 7), b256, 0, stream>>>(
      temps, (long)NG * 128, gatW1, (long)64 * 128, nullptr, 0, hd1, (long)NG * 64,
      NG, 64, 128, 0);
  att_scores_k<64><<<dim3(NG, 7), 64, 0, stream>>>(hd1, gatas1, gatad1, as1, ad1);
  edge_p_k<<<dim3(EB, 7), b256, 0, stream>>>(ed, as1, ad1, p1, den1);
  gat_agg_k<64, 2><<<dim3(NG, 7), 64, 0, stream>>>(rp, ce, ed, p1, den1, hd1, gatb1, xs1);

  // ---- TA chain 2 (sequential, H=64) ----
  hipMemcpyAsync(xdenc, xs1, (size_t)NG * 64 * 4, hipMemcpyDeviceToDevice, stream);
  split_t_k<64><<<64, b256, 0, stream>>>(xs1, xt2hi, xt2lo);
  for (int j = 0; j < 6; ++j) {
    ta_gemm_k<64><<<dim3(16, 1, SK_TA), b256, 0, stream>>>(
        tacw1 + (size_t)j * NG * NG, xt2hi, xt2lo, ypT);
    bool last = (j == 5);
    bn_mask_k<<<64, b256, 0, stream>>>(ypT, SK_TA, 64,
        tacb1 + (size_t)j * NG, tag1 + j * 64, tabe1 + j * 64,
        xs1 + (size_t)(j + 1) * NG * 64, xdenc + (size_t)(j + 1) * NG * 64,
        last ? nullptr : xt2hi, last ? nullptr : xt2lo);
  }

  // ---- Decoder_D (MFMA, batched) ----
  proj_gemm_k<128><<<dim3(16, 1, 7), b256, 0, stream>>>(
      xdenc, (long)NG * 64, ddW0, (long)128 * 64, ddb0, 128, dh, (long)NG * 128,
      NG, 128, 64, 1);
  proj_gemm_k<128><<<dim3(16, 2, 7), b256, 0, stream>>>(
      dh, (long)NG * 128, ddW1, (long)256 * 128, ddb1, 256, xdrec, (long)NG * 256,
      NG, 256, 128, 2);

  // ---- losses + output ----
  loss_d_k<<<512, b256, 0, stream>>>(x_d, xdrec, scal);
  loss_t_k<<<dim3(128, 6), b256, 0, stream>>>(xdrec, scal);
  concat_k<<<(NG * 96 + 255) / 256, b256, 0, stream>>>(xgenc, xdenc, out);
  fin_k<<<1, 1, 0, stream>>>(scal, out);
}